// Round 14
// baseline (83.177 us; speedup 1.0000x reference)
//
#include <hip/hip_runtime.h>
#include <stdint.h>

#define BN       16384
#define NTILES   256     // BN/64
#define NB       64      // norm buckets
#define KOUT     16
#define MARGIN   0.01f   // certified slack >> max fp32 eval error (~4e-5)

typedef float v2f __attribute__((ext_vector_type(2)));
union F4 { float4 f4; v2f p[2]; float f[4]; };

// ---- workspace layout (bytes) ----
#define WS_TAB    0                         // float4[BN]    262144
#define WS_IDX    (WS_TAB + BN * 16)        // u32[BN]        65536
#define WS_BND    (WS_IDX + BN * 4)         // float2[NTILES]  2048
#define WS_HIST   (WS_BND + NTILES * 8)     // u32[64][NB]    16384
#define WS_HMAX   (WS_HIST + 64 * NB * 4)   // u32[64][NB]    16384

// sortable key of float bits (ascending uint == ascending float)
__device__ __forceinline__ unsigned key_u(unsigned u) {
    return u ^ ((unsigned)((int)u >> 31) | 0x80000000u);
}
__device__ __forceinline__ unsigned wshr1(unsigned v, unsigned oldv) {
    return (unsigned)__builtin_amdgcn_update_dpp((int)oldv, (int)v, 0x138 /*WAVE_SHR:1*/,
                                                 0xF, 0xF, false);
}
// full-wave rotate by 1 (WAVE_ROR:1), 64-bit value: 2 DPP moves, pure VALU
__device__ __forceinline__ double wror1_f64(double v) {
    const unsigned long long u = (unsigned long long)__double_as_longlong(v);
    unsigned lo = (unsigned)u, hi = (unsigned)(u >> 32);
    lo = (unsigned)__builtin_amdgcn_update_dpp((int)lo, (int)lo, 0x13C, 0xF, 0xF, false);
    hi = (unsigned)__builtin_amdgcn_update_dpp((int)hi, (int)hi, 0x13C, 0xF, 0xF, false);
    return __longlong_as_double((long long)(((unsigned long long)hi << 32) | lo));
}
#define RL16(T) __uint_as_float((unsigned)__builtin_amdgcn_readlane(__float_as_int(T), 16))

// exact np-order squared norm: (x^2 + y^2) + z^2
__device__ __forceinline__ float sq_of(float gx, float gy, float gz) {
    return __fadd_rn(__fadd_rn(__fmul_rn(gx, gx), __fmul_rn(gy, gy)), __fmul_rn(gz, gz));
}
__device__ __forceinline__ int bucket_of(float sq) {
    const float rho = __fsqrt_rn(sq);
    int b = (int)(64.0f * (1.0f - rho * 0.2f));  // edges rho_b = 5*(1-b/64)
    return (b < 0) ? 0 : ((b > 63) ? 63 : b);
}

// Lexicographic (pair asc, idx asc) sorted insert -> scan-order independent.
#define DRAIN(m, p, jvec, T, J)                                                     \
    while (m) {                                                                     \
        const int b_ = (int)__builtin_ctzll(m);                                     \
        m &= m - 1;                                                                 \
        const float pc_ = __uint_as_float(                                          \
            (unsigned)__builtin_amdgcn_readlane(__float_as_int(p), b_));            \
        const unsigned jc_ = (unsigned)__builtin_amdgcn_readlane((int)(jvec), b_);  \
        const float Tup_ =                                                          \
            __uint_as_float(wshr1(__float_as_uint(T), 0xFF800000u /*-inf*/));       \
        const unsigned Jup_ = wshr1((J), 0u);                                       \
        const bool lt_ = (pc_ < Tup_) || ((pc_ == Tup_) && (jc_ < Jup_));           \
        const float Tn_ = lt_ ? Tup_ : pc_;                                         \
        const unsigned Jn_ = lt_ ? Jup_ : jc_;                                      \
        const bool sel_ = (pc_ < (T)) || ((pc_ == (T)) && (jc_ < (J)));             \
        (T) = sel_ ? Tn_ : (T);                                                     \
        (J) = sel_ ? Jn_ : (J);                                                     \
    }

// d2 = ((2*dot + nsq_q) + nsq_j) packed for 2 queries, bitwise == reference chain.
#define EVALC(c, d2)                                                                \
    asm("v_pk_mul_f32 %0, %1, %2 op_sel:[0,0] op_sel_hi:[0,1]"                      \
        : "=v"(d2) : "v"((c).p[0]), "v"(c0A));                                      \
    asm("v_pk_fma_f32 %0, %1, %2, %0 op_sel:[1,0,0] op_sel_hi:[1,1,1]"              \
        : "+v"(d2) : "v"((c).p[0]), "v"(c1A));                                      \
    asm("v_pk_fma_f32 %0, %1, %2, %0 op_sel:[0,0,0] op_sel_hi:[0,1,1]"              \
        : "+v"(d2) : "v"((c).p[1]), "v"(c2A));                                      \
    asm("v_pk_add_f32 %0, %0, %1" : "+v"(d2) : "v"(nsq01));                         \
    asm("v_pk_add_f32 %0, %0, %1 op_sel:[0,1] op_sel_hi:[1,1]"                      \
        : "+v"(d2) : "v"((c).p[1]));

#define TILE_AT(t)                                                                  \
    F4 c; c.f4 = tab[(t) * 64 + lane];                                              \
    const unsigned jvec = idxarr[(t) * 64 + lane];                                  \
    v2f d2; EVALC(c, d2)

#define PROCESS_LOADED()                                                            \
    do {                                                                            \
        uint64_t m0 = __ballot(d2[0] <= fF0);                                       \
        uint64_t m1 = __ballot(d2[1] <= fF1);                                       \
        if (m0 | m1) {                                                              \
            const float p0 = d2[0], p1 = d2[1];                                     \
            DRAIN(m0, p0, jvec, T0, J0)                                             \
            DRAIN(m1, p1, jvec, T1, J1)                                             \
            fF0 = RL16(T0); thr0 = __fsub_rn(-fF0, MARGIN);                         \
            fF1 = RL16(T1); thr1 = __fsub_rn(-fF1, MARGIN);                         \
        }                                                                           \
    } while (0)

// Wave-parallel exact sort of 64 (p, j) pairs by (p asc, j asc).
// Rank via 63 DPP wave-rotations + f64 compare (ordering scalar key*16384+j,
// exact <= 2^46): pure VALU, no LDS pipe. Only the final scatter touches LDS.
__device__ __forceinline__ void presort64(float p, unsigned j, int lane, double* sw,
                                          float& T, unsigned& J) {
    const double dm = (double)key_u(__float_as_uint(p)) * 16384.0 + (double)j;
    double rot = dm;
    unsigned rank = 0;
#pragma unroll
    for (int s = 0; s < 63; ++s) {
        rot = wror1_f64(rot);
        rank += (rot < dm) ? 1u : 0u;
    }
    sw[rank] = __longlong_as_double(
        (long long)(((unsigned long long)j << 32) | __float_as_uint(p)));
    const unsigned long long v = (unsigned long long)__double_as_longlong(sw[lane]);
    T = __uint_as_float((unsigned)(v & 0xFFFFFFFFull));
    J = (unsigned)(v >> 32);
}

// ---- prep 1: per-block histogram + per-bucket max norm (64 blocks, parallel) ----
__global__ __launch_bounds__(256) void k_hist(const float* __restrict__ x,
                                              unsigned* __restrict__ hist,
                                              unsigned* __restrict__ hmax) {
    __shared__ unsigned h[NB], m[NB];
    const int tid = threadIdx.x;
    if (tid < NB) { h[tid] = 0u; m[tid] = 0u; }
    __syncthreads();
    const int i = blockIdx.x * 256 + tid;
    const float sq = sq_of(x[3 * i], x[3 * i + 1], x[3 * i + 2]);
    const int b = bucket_of(sq);
    atomicAdd(&h[b], 1u);
    atomicMax(&m[b], __float_as_uint(sq));  // sq>0: float bits monotone
    __syncthreads();
    if (tid < NB) {
        hist[blockIdx.x * NB + tid] = h[tid];
        hmax[blockIdx.x * NB + tid] = m[tid];
    }
}

// ---- prep 2 (fused): each block recomputes bases + its column prefix from the
// L2-hot hist; block 0 also computes suffix max + per-tile bounds. Deterministic
// positions; within-bucket order nondeterministic (harmless: lexicographic DRAIN).
__global__ __launch_bounds__(256) void k_scatter(const float* __restrict__ x,
                                                 const unsigned* __restrict__ hist,
                                                 const unsigned* __restrict__ hmax,
                                                 float4* __restrict__ tab,
                                                 unsigned* __restrict__ idxarr,
                                                 float2* __restrict__ bnd) {
    __shared__ unsigned tot_s[NB], pre_s[NB], basev[NB + 1], c[NB], sfx[NB];
    const int tid = threadIdx.x;
    const int g0 = (int)blockIdx.x;
    if (tid < NB) {
        unsigned s = 0, pre = 0;
        for (int g = 0; g < 64; ++g) {
            const unsigned hh = hist[g * NB + tid];
            pre += (g < g0) ? hh : 0u;
            s += hh;
        }
        tot_s[tid] = s;
        pre_s[tid] = pre;
        if (g0 == 0) {
            unsigned mx = 0;
            for (int g = 0; g < 64; ++g) {
                const unsigned w = hmax[g * NB + tid];
                mx = (w > mx) ? w : mx;
            }
            sfx[tid] = mx;
        }
    }
    __syncthreads();
    if (tid == 0) {
        unsigned s = 0;
        for (int b = 0; b < NB; ++b) { basev[b] = s; s += tot_s[b]; }
        basev[NB] = s;
        if (g0 == 0) {
            unsigned M = 0;
            for (int b = NB - 1; b >= 0; --b) {
                const unsigned w = sfx[b]; M = (w > M) ? w : M; sfx[b] = M;
            }
        }
    }
    __syncthreads();
    if (tid < NB) c[tid] = basev[tid] + pre_s[tid];
    __syncthreads();
    const int i = g0 * 256 + tid;
    const float gx = x[3 * i], gy = x[3 * i + 1], gz = x[3 * i + 2];
    const float sq = sq_of(gx, gy, gz);
    const int b = bucket_of(sq);
    const unsigned pos = atomicAdd(&c[b], 1u);
    tab[pos] = make_float4(gx, gy, gz, -sq);
    idxarr[pos] = (unsigned)i;
    if (g0 == 0) {  // per-tile bound: bucket of position 64*tid -> suffix bucket max
        const unsigned posn = (unsigned)tid * 64u;
        int b2 = 0;
        for (int bb = 0; bb < NB; ++bb) b2 = (basev[bb] <= posn) ? bb : b2;
        const float B = __uint_as_float(sfx[b2]);
        const float sqB_up = __uint_as_float(__float_as_uint(__fsqrt_rn(B)) + 2u);
        bnd[tid] = make_float2(B, sqB_up);
    }
}

// ---- main kernel: R13 structure, DPP presort ----
__global__ __launch_bounds__(256) void knn_far_kernel(
    const float* __restrict__ x, const float4* __restrict__ tab,
    const unsigned* __restrict__ idxarr, const float2* __restrict__ bnd,
    float* __restrict__ out_d, float* __restrict__ out_i) {
    __shared__ double swall[4 * 64];
    const int tid  = threadIdx.x;
    const int lane = tid & 63;
    const int wid  = tid >> 6;
    double* sw = swall + wid * 64;
    const int q0 = (blockIdx.x * 4 + wid) * 2;
    const int q1 = q0 + 1;

    const float a0 = x[3 * q0], a1 = x[3 * q0 + 1], a2 = x[3 * q0 + 2];
    const float b0 = x[3 * q1], b1 = x[3 * q1 + 1], b2 = x[3 * q1 + 2];
    const float sq0 = sq_of(a0, a1, a2), sq1 = sq_of(b0, b1, b2);
    const v2f nsq01 = {-sq0, -sq1};
    const v2f c0A = {2.0f * a0, 2.0f * b0};
    const v2f c1A = {2.0f * a1, 2.0f * b1};
    const v2f c2A = {2.0f * a2, 2.0f * b2};
    // upper-bounded 2*|q| for the certificate
    const float twor0 = 2.0f * __uint_as_float(__float_as_uint(__fsqrt_rn(sq0)) + 2u);
    const float twor1 = 2.0f * __uint_as_float(__float_as_uint(__fsqrt_rn(sq1)) + 2u);

    float T0, T1; unsigned J0, J1;
    float fF0, fF1, thr0, thr1;

    {   // tile 0: seed via DPP-rank presort (no insert flood, no LDS rank loop)
        TILE_AT(0)
        presort64(d2[0], jvec, lane, sw, T0, J0);
        presort64(d2[1], jvec, lane, sw, T1, J1);
        fF0 = RL16(T0); thr0 = __fsub_rn(-fF0, MARGIN);
        fF1 = RL16(T1); thr1 = __fsub_rn(-fF1, MARGIN);
    }
#pragma unroll
    for (int t = 1; t < 4; ++t) {  // rest of the seed region (top-256 norms)
        TILE_AT(t)
        PROCESS_LOADED();
    }
    for (int t = 4; t < NTILES; ++t) {
        const float2 bd = bnd[t];  // B = max sq_p over positions >= 64t (bucket-granular)
        const float u0 = __builtin_fmaf(twor0, bd.y, __fadd_rn(sq0, bd.x));
        const float u1 = __builtin_fmaf(twor1, bd.y, __fadd_rn(sq1, bd.x));
        if (u0 < thr0 && u1 < thr1) break;  // certified: no future point can matter
        TILE_AT(t)
        PROCESS_LOADED();
    }

    if (lane >= 1 && lane <= KOUT) {  // ranks 1..16 (rank 0 dropped by reference)
        const int r = lane - 1;
        out_d[q0 * KOUT + r] = T0;
        out_i[q0 * KOUT + r] = (float)J0;
        out_d[q1 * KOUT + r] = T1;
        out_i[q1 * KOUT + r] = (float)J1;
    }
}

extern "C" void kernel_launch(void* const* d_in, const int* in_sizes, int n_in,
                              void* d_out, int out_size, void* d_ws, size_t ws_size,
                              hipStream_t stream) {
    const float* x = (const float*)d_in[0];
    char* ws = (char*)d_ws;
    float4*   tab    = (float4*)(ws + WS_TAB);
    unsigned* idxarr = (unsigned*)(ws + WS_IDX);
    float2*   bnd    = (float2*)(ws + WS_BND);
    unsigned* hist   = (unsigned*)(ws + WS_HIST);
    unsigned* hmax   = (unsigned*)(ws + WS_HMAX);
    float* out_d = (float*)d_out;
    float* out_i = out_d + (size_t)BN * KOUT;

    hipLaunchKernelGGL(k_hist,    dim3(64), dim3(256), 0, stream, x, hist, hmax);
    hipLaunchKernelGGL(k_scatter, dim3(64), dim3(256), 0, stream, x, hist, hmax,
                       tab, idxarr, bnd);
    hipLaunchKernelGGL(knn_far_kernel, dim3(BN / 8), dim3(256), 0, stream,
                       x, tab, idxarr, bnd, out_d, out_i);
}